// Round 5
// baseline (145.342 us; speedup 1.0000x reference)
//
#include <hip/hip_runtime.h>

#define DIN 1024
#define LSEQ 2048

typedef _Float16 f16;
typedef _Float16 half8 __attribute__((ext_vector_type(8)));
typedef float floatx4 __attribute__((ext_vector_type(4)));

__device__ __forceinline__ void async_ld16(const void* g, void* l) {
  __builtin_amdgcn_global_load_lds(
      (const __attribute__((address_space(1))) void*)g,
      (__attribute__((address_space(3))) void*)l, 16, 0, 0);
}

__device__ __forceinline__ float fast_exp2(float x) {
#if __has_builtin(__builtin_amdgcn_exp2f)
  return __builtin_amdgcn_exp2f(x);
#else
  return exp2f(x);
#endif
}

__device__ __forceinline__ unsigned int pack2_f16(float a, float b) {
#if __has_builtin(__builtin_amdgcn_cvt_pkrtz)
  typedef __fp16 fp16x2 __attribute__((ext_vector_type(2)));
  fp16x2 h = __builtin_amdgcn_cvt_pkrtz(a, b);
  return __builtin_bit_cast(unsigned int, h);
#else
  union { f16 h[2]; unsigned int u; } pk;
  pk.h[0] = (f16)a; pk.h[1] = (f16)b;
  return pk.u;
#endif
}

// ---------------- Kernel 1: W [k][n] fp32 -> Wt [n][k] fp16 ----------------
__global__ void __launch_bounds__(256) kwt(const float* __restrict__ wq,
                                           const float* __restrict__ wk,
                                           const float* __restrict__ wv,
                                           f16* __restrict__ wqt,
                                           f16* __restrict__ wkt,
                                           f16* __restrict__ wvt) {
  __shared__ float t[32][33];
  const float* src = blockIdx.z == 0 ? wq : (blockIdx.z == 1 ? wk : wv);
  f16* dst = blockIdx.z == 0 ? wqt : (blockIdx.z == 1 ? wkt : wvt);
  int k0 = blockIdx.x * 32, n0 = blockIdx.y * 32;
  int tx = threadIdx.x, ty = threadIdx.y;  // (32,8)
#pragma unroll
  for (int r = 0; r < 4; ++r)
    t[ty + r * 8][tx] = src[(k0 + ty + r * 8) * DIN + n0 + tx];
  __syncthreads();
#pragma unroll
  for (int r = 0; r < 4; ++r)
    dst[(n0 + ty + r * 8) * DIN + k0 + tx] = (f16)t[tx][ty + r * 8];
}

// ------------- Kernel 2: C = X(4096x1024) @ W -> Q/K/V fp16 ----------------
__global__ void __launch_bounds__(256) kproj(const float* __restrict__ xq,
                                             const float* __restrict__ xk,
                                             const f16* __restrict__ wqt,
                                             const f16* __restrict__ wkt,
                                             const f16* __restrict__ wvt,
                                             f16* __restrict__ qb,
                                             f16* __restrict__ kb,
                                             f16* __restrict__ vb) {
  __shared__ __align__(16) char As[128 * 128];
  __shared__ __align__(16) char Bs[128 * 128];
  const float* X;
  const f16* W;
  f16* dst;
  int z = blockIdx.z;
  if (z == 0) { X = xq; W = wqt; dst = qb; }
  else if (z == 1) { X = xk; W = wkt; dst = kb; }
  else { X = xk; W = wvt; dst = vb; }
  float oscale = (z == 0) ? 0.18033688011112042f : 1.0f;  // SC only for Q
  int m0 = blockIdx.y * 128, n0 = blockIdx.x * 128;
  int tid = threadIdx.x, lane = tid & 63, wid = tid >> 6;
  int wm = wid >> 1, wn = wid & 1;
  int c15 = lane & 15, g = lane >> 4;
  int l8 = lane >> 3, l7 = lane & 7;
  int kk = 8 * (l7 ^ l8);  // pre-swizzled global k-offset for linear LDS dest
  int swz = (c15 & 7) << 4;
  floatx4 acc[4][4] = {};

  for (int kt = 0; kt < 16; ++kt) {
    int k0 = kt * 64;
#pragma unroll
    for (int cc = 0; cc < 4; ++cc) {
      int c = wid * 4 + cc;
      async_ld16(&W[(n0 + c * 8 + l8) * DIN + k0 + kk], Bs + c * 1024);
    }
    {
      int q = tid & 15;
#pragma unroll
      for (int p = 0; p < 8; ++p) {
        int row = p * 16 + (tid >> 4);
        const float4 v = *(const float4*)&X[(m0 + row) * DIN + k0 + q * 4];
        union { unsigned int u[2]; uint2 v2; } pk;
        pk.u[0] = pack2_f16(v.x, v.y);
        pk.u[1] = pack2_f16(v.z, v.w);
        *(uint2*)(As + row * 128 + ((q * 8) ^ ((row & 7) << 4))) = pk.v2;
      }
    }
    __syncthreads();
#pragma unroll
    for (int ks = 0; ks < 2; ++ks) {
      int koff = (ks * 64 + g * 16) ^ swz;
      half8 af[4], bf[4];
#pragma unroll
      for (int i = 0; i < 4; ++i)
        af[i] = *(const half8*)(As + (wm * 64 + i * 16 + c15) * 128 + koff);
#pragma unroll
      for (int j = 0; j < 4; ++j)
        bf[j] = *(const half8*)(Bs + (wn * 64 + j * 16 + c15) * 128 + koff);
#pragma unroll
      for (int i = 0; i < 4; ++i)
#pragma unroll
        for (int j = 0; j < 4; ++j)
          acc[i][j] = __builtin_amdgcn_mfma_f32_16x16x32_f16(af[i], bf[j], acc[i][j], 0, 0, 0);
    }
    __syncthreads();
  }
#pragma unroll
  for (int i = 0; i < 4; ++i) {
    int mrow = m0 + wm * 64 + i * 16 + 4 * g;
#pragma unroll
    for (int j = 0; j < 4; ++j) {
      int n = n0 + wn * 64 + j * 16 + c15;
      int h = n >> 6, d = n & 63;
#pragma unroll
      for (int r = 0; r < 4; ++r) {
        int m = mrow + r;
        int b = m >> 11, lrow = m & 2047;
        dst[(((b << 4) + h) * 2048 + lrow) * 64 + d] = (f16)(acc[i][j][r] * oscale);
      }
    }
  }
}

// ------------- Kernel 3: V [bh][l][64] -> Vt [bh][64][l] fp16 --------------
__global__ void __launch_bounds__(256) kvt(const f16* __restrict__ vbuf,
                                           f16* __restrict__ vt) {
  __shared__ __align__(16) f16 t[64][72];
  int l0 = blockIdx.x * 64, bh = blockIdx.y;
  int tid = threadIdx.x;
  int lrow = tid >> 3, chunk = tid & 7;
#pragma unroll
  for (int p = 0; p < 2; ++p) {
    int l = p * 32 + lrow;
    *(uint4*)&t[l][chunk * 8] =
        *(const uint4*)&vbuf[(bh * 2048 + l0 + l) * 64 + chunk * 8];
  }
  __syncthreads();
#pragma unroll
  for (int p = 0; p < 2; ++p) {
    int d = p * 32 + lrow;
    union { f16 h[8]; uint4 u; } pk;
#pragma unroll
    for (int u = 0; u < 8; ++u) pk.h[u] = t[chunk * 8 + u][d];
    *(uint4*)&vt[(bh * 64 + d) * 2048 + l0 + chunk * 8] = pk.u;
  }
}

// --------------------- Kernel 4: flash attention ---------------------------
// 128 q/block (32/wave, TWO q-sets per wave), KV tile 64, double-buffered K/V.
// Each K-frag and V-frag LDS read feeds 2 MFMAs (one per q-set) -> LDS
// traffic and barrier count per FLOP halve vs 16q/wave. Shift-free softmax.
__global__ void __launch_bounds__(256) kattn(const f16* __restrict__ qb,
                                             const f16* __restrict__ kbuf,
                                             const f16* __restrict__ vt,
                                             float* __restrict__ out) {
  // [0,32768): K/V double buffer (buf*16384 + {K:0, V:8192})
  // [32768, 50176): Q staging 16KB (prologue), then per-wave P strips
  //                 (4 waves x 32q x 136B = 17408B)
  __shared__ __align__(16) char smem[50176];
  char* Qs = smem + 32768;
  char* Ps = smem + 32768;
  float* Ot = (float*)smem;  // epilogue overlay [128][68] f32 = 34816B

  // XCD swizzle: 512 blocks; id&7 = XCD; 4 heads per XCD (2MB K/V in 4MB L2).
  int id = blockIdx.x;
  int wi = id >> 3;                       // 0..63
  int bh = ((id & 7) << 2) | (wi >> 4);   // 4 heads per XCD
  int q0 = (wi & 15) << 7;                // 16 q-blocks of 128

  int tid = threadIdx.x, lane = tid & 63, w = tid >> 6;
  int c15 = lane & 15, g = lane >> 4;
  int l8 = lane >> 3, l7 = lane & 7;
  int kk = 8 * (l7 ^ l8);
  int swz = (c15 & 7) << 4;

  const f16* kbase = kbuf + (size_t)bh * 2048 * 64;
  const f16* vbase = vt + (size_t)bh * 64 * 2048;

  auto stage = [&](int buf, int kv0) {
#pragma unroll
    for (int cc = 0; cc < 2; ++cc) {
      int c = w * 2 + cc;
      async_ld16(&kbase[(kv0 + c * 8 + l8) * 64 + kk],
                 smem + buf * 16384 + c * 1024);
      async_ld16(&vbase[(c * 8 + l8) * 2048 + kv0 + kk],
                 smem + buf * 16384 + 8192 + c * 1024);
    }
  };

  // prologue: Q (16KB, 16 chunks) + tile0
#pragma unroll
  for (int cc = 0; cc < 4; ++cc) {
    int c = w * 4 + cc;
    async_ld16(&qb[((size_t)bh * 2048 + q0 + c * 8 + l8) * 64 + kk],
               Qs + c * 1024);
  }
  stage(0, 0);
  __syncthreads();
  half8 qf[2][2];
#pragma unroll
  for (int s = 0; s < 2; ++s)
#pragma unroll
    for (int ks = 0; ks < 2; ++ks)
      qf[s][ks] = *(const half8*)(Qs + (w * 32 + s * 16 + c15) * 128 +
                                  ((ks * 64 + g * 16) ^ swz));
  __syncthreads();  // all qf reads done before anyone writes P over Qs

  float ls0 = 0.f, ls1 = 0.f;
  floatx4 oacc[2][4] = {};
  char* Pw = Ps + w * 4352;  // 32 rows x 136B

  int buf = 0;
  for (int t = 0; t < 32; ++t) {
    if (t < 31) stage(buf ^ 1, (t + 1) * 64);  // prefetch next tile
    const char* Ks = smem + buf * 16384;
    const char* Vs = Ks + 8192;

    // S^T = K @ Q^T for both q-sets: rows kv (16i+4g+r), col q
    floatx4 st[2][4] = {};
    __builtin_amdgcn_s_setprio(1);
#pragma unroll
    for (int ks = 0; ks < 2; ++ks) {
      int koff = (ks * 64 + g * 16) ^ swz;
#pragma unroll
      for (int i = 0; i < 4; ++i) {
        half8 kf = *(const half8*)(Ks + (i * 16 + c15) * 128 + koff);
        st[0][i] = __builtin_amdgcn_mfma_f32_16x16x32_f16(kf, qf[0][ks], st[0][i], 0, 0, 0);
        st[1][i] = __builtin_amdgcn_mfma_f32_16x16x32_f16(kf, qf[1][ks], st[1][i], 0, 0, 0);
      }
    }
    __builtin_amdgcn_s_setprio(0);

    // shift-free softmax per q-set: p = exp2(s)
    unsigned int pu[2][8];
#pragma unroll
    for (int s = 0; s < 2; ++s) {
      float ps0 = 0.f, ps1 = 0.f;
#pragma unroll
      for (int x = 0; x < 8; ++x) {
        float p0 = fast_exp2(st[s][x >> 1][(x & 1) * 2]);
        float p1 = fast_exp2(st[s][x >> 1][(x & 1) * 2 + 1]);
        ps0 += p0;
        ps1 += p1;
        pu[s][x] = pack2_f16(p0, p1);
      }
      if (s == 0) ls0 += ps0 + ps1; else ls1 += ps0 + ps1;
    }

    // P^T -> per-wave LDS strip [32 q][136B]; row = s*16+c15, kv byte = 32i+8g
#pragma unroll
    for (int s = 0; s < 2; ++s)
#pragma unroll
      for (int i = 0; i < 4; ++i) {
        union { unsigned int u[2]; uint2 v; } pk;
        pk.u[0] = pu[s][2 * i]; pk.u[1] = pu[s][2 * i + 1];
        *(uint2*)(Pw + (s * 16 + c15) * 136 + 32 * i + 8 * g) = pk.v;
      }

    // O^T += V^T @ P^T for both q-sets; V-frags shared
    __builtin_amdgcn_s_setprio(1);
#pragma unroll
    for (int kb = 0; kb < 2; ++kb) {
      int koff = (kb * 64 + g * 16) ^ swz;
      half8 pf0 = *(const half8*)(Pw + (0 + c15) * 136 + kb * 64 + 16 * g);
      half8 pf1 = *(const half8*)(Pw + (16 + c15) * 136 + kb * 64 + 16 * g);
#pragma unroll
      for (int df = 0; df < 4; ++df) {
        half8 vf = *(const half8*)(Vs + (df * 16 + c15) * 128 + koff);
        oacc[0][df] = __builtin_amdgcn_mfma_f32_16x16x32_f16(vf, pf0, oacc[0][df], 0, 0, 0);
        oacc[1][df] = __builtin_amdgcn_mfma_f32_16x16x32_f16(vf, pf1, oacc[1][df], 0, 0, 0);
      }
    }
    __builtin_amdgcn_s_setprio(0);
    __syncthreads();  // drains prefetch vmcnt; next buf ready
    buf ^= 1;
  }

  // cross-g reduce of lsums
  ls0 += __shfl_xor(ls0, 16, 64);
  ls0 += __shfl_xor(ls0, 32, 64);
  ls1 += __shfl_xor(ls1, 16, 64);
  ls1 += __shfl_xor(ls1, 32, 64);
  float inv0 = 1.f / ls0, inv1 = 1.f / ls1;

  // transpose O^T through LDS, coalesced fp32 store
#pragma unroll
  for (int s = 0; s < 2; ++s) {
    float inv = s == 0 ? inv0 : inv1;
#pragma unroll
    for (int df = 0; df < 4; ++df) {
      floatx4 v = oacc[s][df] * inv;
      *(floatx4*)&Ot[(w * 32 + s * 16 + c15) * 68 + df * 16 + 4 * g] = v;
    }
  }
  __syncthreads();
  int b = bh >> 4, h = bh & 15;
  int row = tid >> 1, seg = tid & 1;  // 2 threads per row, 32 floats each
  float* dstp = &out[(b * 2048 + q0 + row) * 1024 + h * 64 + seg * 32];
  const float* srcl = &Ot[row * 68 + seg * 32];
#pragma unroll
  for (int u = 0; u < 8; ++u)
    *(float4*)(dstp + u * 4) = *(const float4*)(srcl + u * 4);
}

// ---------------------------------------------------------------------------
extern "C" void kernel_launch(void* const* d_in, const int* in_sizes, int n_in,
                              void* d_out, int out_size, void* d_ws, size_t ws_size,
                              hipStream_t stream) {
  const float* xq = (const float*)d_in[0];
  const float* xk = (const float*)d_in[1];
  const float* wq = (const float*)d_in[2];
  const float* wk = (const float*)d_in[3];
  const float* wv = (const float*)d_in[4];
  char* ws = (char*)d_ws;
  f16* wqt = (f16*)(ws + (0ull << 20));
  f16* wkt = (f16*)(ws + (2ull << 20));
  f16* wvt = (f16*)(ws + (4ull << 20));
  f16* qbuf = (f16*)(ws + (6ull << 20));
  f16* kbuf = (f16*)(ws + (14ull << 20));
  f16* vbuf = (f16*)(ws + (22ull << 20));
  f16* vtb  = (f16*)(ws + (30ull << 20));

  kwt<<<dim3(32, 32, 3), dim3(32, 8), 0, stream>>>(wq, wk, wv, wqt, wkt, wvt);
  kproj<<<dim3(8, 32, 3), 256, 0, stream>>>(xq, xk, wqt, wkt, wvt, qbuf, kbuf, vbuf);
  kvt<<<dim3(32, 32), 256, 0, stream>>>(vbuf, vtb);
  kattn<<<512, 256, 0, stream>>>(qbuf, kbuf, vtb, (float*)d_out);
}